// Round 1
// baseline (152.095 us; speedup 1.0000x reference)
//
#include <hip/hip_runtime.h>

// SpectralRegularizer closed form (verified exact, absmax 0.0):
//   All k_mag fall in searchsorted bin 1 -> spectrum = [0, S1, 0...0] (len 32)
//   S1 = sum_{b,c} E_rfft / (128*128*65 * 4)
//   E_rfft(slice) = (128^3 * sum x^2 + 128^2 * (sum A^2 + sum B^2)) / 2
//     A[x,y] = sum_z x[x,y,z];  B[x,y] = sum_z (-1)^z x[x,y,z]
//   out = 0.01 * decay_const + 0.001 * S1/31
//   decay_const = mean_{k=9..31} (k^{-5/3} / (9^{-5/3}+1e-8))^2  (data-independent)
//
// R3 structure: latency-oriented rework of the reduce kernel.
//   - 2048 blocks x 256 thr -> 32 waves/CU (max occupancy; was 16/CU).
//   - tile = 4 rows (2 KB). Lane mapping: row = lane>>4, chunk = lane&15.
//     Each lane loads TWO independent float4 (bytes 0-255 and 256-511 of its
//     row) -> 2 loads in flight per wave-iteration, per-lane s/a accumulate
//     over 8 floats BEFORE any cross-lane op.
//   - reduction: 4 shuffle steps over 16-lane groups x 2 values = 8 shuffles
//     per 2 KB (was 10 per 1 KB) -> shorter dependent chains.
//   No memset, no atomics: kernel1 overwrites per-block partials (d_ws),
//   kernel2 (single block) reduces partials + emits the scalar.

#define NBLOCKS 2048
#define N_TILES (12 * 128 * 128 / 4)   // tile = 4 rows of 128 floats = 2 KB

__global__ __launch_bounds__(256, 8) void spectral_reduce(
        const float* __restrict__ x, double* __restrict__ partials) {
    // partials[b]          = block b's sum x^2
    // partials[NBLOCKS+b]  = block b's sum over rows (rowsum^2 + rowalt^2)
    const int lane   = threadIdx.x & 63;
    const int waveId = (blockIdx.x * blockDim.x + threadIdx.x) >> 6;
    const int nWaves = (gridDim.x * blockDim.x) >> 6;   // 8192

    const int rowq  = lane >> 4;   // which of the tile's 4 rows
    const int chunk = lane & 15;   // float4 slot within a 256 B half-row

    float acc_sq = 0.0f;   // every lane: own x^2 partial
    float acc_pl = 0.0f;   // lanes 0,16,32,48: row results

    const float4* __restrict__ x4 = (const float4*)x;

    for (int p = waveId; p < N_TILES; p += nWaves) {       // 6 iterations
        const int base = p * 128 + rowq * 32 + chunk;      // float4 units
        const float4 u = x4[base];        // row bytes [0,256)
        const float4 v = x4[base + 16];   // row bytes [256,512)  (z offset 64, even)
        float s = (u.x + u.y + u.z + u.w) + (v.x + v.y + v.z + v.w);
        float a = (u.x - u.y + u.z - u.w) + (v.x - v.y + v.z - v.w);
        acc_sq += u.x * u.x + u.y * u.y + u.z * u.z + u.w * u.w
                + v.x * v.x + v.y * v.y + v.z * v.z + v.w * v.w;
        // reduce s,a within each 16-lane group (one row per group)
        #pragma unroll
        for (int off = 1; off < 16; off <<= 1) {
            s += __shfl_xor(s, off, 64);
            a += __shfl_xor(a, off, 64);
        }
        if (chunk == 0) acc_pl += s * s + a * a;
    }

    // full-wave reduce both accumulators
    #pragma unroll
    for (int off = 1; off < 64; off <<= 1) {
        acc_sq += __shfl_xor(acc_sq, off, 64);
        acc_pl += __shfl_xor(acc_pl, off, 64);
    }

    __shared__ float s_sq[4], s_pl[4];
    const int w = threadIdx.x >> 6;
    if (lane == 0) { s_sq[w] = acc_sq; s_pl[w] = acc_pl; }
    __syncthreads();
    if (threadIdx.x == 0) {
        float tsq = 0.0f, tpl = 0.0f;
        #pragma unroll
        for (int i = 0; i < 4; ++i) { tsq += s_sq[i]; tpl += s_pl[i]; }
        partials[blockIdx.x]           = (double)tsq;   // plain store, no init needed
        partials[NBLOCKS + blockIdx.x] = (double)tpl;
    }
}

__global__ __launch_bounds__(256) void spectral_finalize(
        const double* __restrict__ partials, float* __restrict__ out) {
    const int tid  = threadIdx.x;
    const int lane = tid & 63;

    double sq = 0.0, pl = 0.0;
    #pragma unroll
    for (int i = 0; i < 8; ++i) {                 // 2048 partials, stride-256 coalesced
        sq += partials[tid + 256 * i];
        pl += partials[NBLOCKS + tid + 256 * i];
    }
    #pragma unroll
    for (int off = 1; off < 64; off <<= 1) {
        sq += __shfl_xor(sq, off, 64);
        pl += __shfl_xor(pl, off, 64);
    }

    __shared__ double w_sq[4], w_pl[4];
    const int w = tid >> 6;
    if (lane == 0) { w_sq[w] = sq; w_pl[w] = pl; }
    __syncthreads();

    if (tid == 0) {
        const double sum_sq = w_sq[0] + w_sq[1] + w_sq[2] + w_sq[3];
        const double plane  = w_pl[0] + w_pl[1] + w_pl[2] + w_pl[3];

        const double E  = (2097152.0 * sum_sq + 16384.0 * plane) * 0.5;  // 128^3, 128^2
        const double S1 = E / (128.0 * 128.0 * 65.0 * 4.0);
        const double cascade = S1 / 31.0;

        const double slope = -5.0 / 3.0;
        const double e0 = pow(9.0, slope) + 1e-8;
        double ss = 0.0;
        for (int k = 9; k < 32; ++k) {
            const double en = pow((double)k, slope) / e0;
            ss += en * en;
        }
        const double decay = ss / 23.0;

        out[0] = (float)(0.01 * decay + 0.001 * cascade);
    }
}

extern "C" void kernel_launch(void* const* d_in, const int* in_sizes, int n_in,
                              void* d_out, int out_size, void* d_ws, size_t ws_size,
                              hipStream_t stream) {
    const float* x   = (const float*)d_in[0];
    double* partials = (double*)d_ws;    // 2*NBLOCKS doubles = 32 KB, fully overwritten
    float* out       = (float*)d_out;

    spectral_reduce<<<NBLOCKS, 256, 0, stream>>>(x, partials);
    spectral_finalize<<<1, 256, 0, stream>>>(partials, out);
}